// Round 4
// baseline (363.007 us; speedup 1.0000x reference)
//
#include <hip/hip_runtime.h>

#define CDIM 512
#define NDIM 4096
#define BATCH 4

using bf8v = __attribute__((ext_vector_type(8))) __bf16;
using f4v  = __attribute__((ext_vector_type(4))) float;

typedef __attribute__((address_space(1))) unsigned int gu32;
typedef __attribute__((address_space(3))) unsigned int lu32;

static __device__ __forceinline__ unsigned short f2bf(float f) {
  unsigned int u = __float_as_uint(f);
  u += 0x7fffu + ((u >> 16) & 1u);   // round-to-nearest-even
  return (unsigned short)(u >> 16);
}

// inline-asm LDS read: invisible to SIInsertWaitcnts' LDS-DMA tracking, so no
// conservative vmcnt(0) is inserted while global_load_lds prefetches are in
// flight.  Data validity is guaranteed by the explicit counted vmcnt +
// barrier + lgkmcnt protocol in the K-loop.
static __device__ __forceinline__ bf8v lds_read16(const unsigned short* p) {
  bf8v r;
  unsigned off = (unsigned)(unsigned long long)p;
  asm volatile("ds_read_b128 %0, %1" : "=v"(r) : "v"(off));
  return r;
}

// ---------------- GN pass 1: per-(b,g) mean/rstd ----------------
__global__ __launch_bounds__(256) void gn_stats_kernel(
    const float* __restrict__ x, float* __restrict__ stats) {
  const int tid = threadIdx.x;
  const float4* xv = (const float4*)(x + (long)blockIdx.x * 65536);
  float s = 0.f, ss = 0.f;
  for (int i = tid; i < 16384; i += 256) {
    float4 d = xv[i];
    s  += d.x + d.y + d.z + d.w;
    ss += d.x * d.x + d.y * d.y + d.z * d.z + d.w * d.w;
  }
#pragma unroll
  for (int off = 32; off; off >>= 1) {
    s  += __shfl_down(s, off);
    ss += __shfl_down(ss, off);
  }
  __shared__ float red[8];
  if ((tid & 63) == 0) { red[tid >> 6] = s; red[4 + (tid >> 6)] = ss; }
  __syncthreads();
  if (tid == 0) {
    float S  = red[0] + red[1] + red[2] + red[3];
    float SS = red[4] + red[5] + red[6] + red[7];
    float mean = S * (1.f / 65536.f);
    float var  = SS * (1.f / 65536.f) - mean * mean;
    stats[blockIdx.x * 2]     = mean;
    stats[blockIdx.x * 2 + 1] = rsqrtf(var + 1e-6f);
  }
}

// ---------------- GN pass 2: normalize + transpose, fp32 [C,N] -> bf16 [N,C] ----------------
__global__ __launch_bounds__(256) void gn_transpose_kernel(
    const float* __restrict__ x, const float* __restrict__ gs,
    const float* __restrict__ gb, const float* __restrict__ stats,
    unsigned short* __restrict__ hT) {
  __shared__ float t[64][65];
  const int tid = threadIdx.x;
  const int b = blockIdx.z;
  const long bbx = (long)b * ((long)CDIM * NDIM);
  const int n0 = blockIdx.x * 64, c0 = blockIdx.y * 64;
  for (int k = 0; k < 4; ++k) {
    int it = tid + k * 256;
    int c = it >> 4, no = (it & 15) << 2;
    int ch = c0 + c;
    int g = ch >> 4;
    float mean = stats[(b * 32 + g) * 2];
    float rstd = stats[(b * 32 + g) * 2 + 1];
    float a  = rstd * gs[ch];
    float bb = gb[ch] - mean * a;
    float4 d = *(const float4*)&x[bbx + (long)ch * NDIM + n0 + no];
    t[no + 0][c] = d.x * a + bb;
    t[no + 1][c] = d.y * a + bb;
    t[no + 2][c] = d.z * a + bb;
    t[no + 3][c] = d.w * a + bb;
  }
  __syncthreads();
  const long bbh = (long)b * ((long)NDIM * CDIM);
  for (int k = 0; k < 2; ++k) {
    int it = tid + k * 256;
    int n = it >> 3, co = (it & 7) << 3;
    unsigned int ow[4];
#pragma unroll
    for (int j = 0; j < 4; ++j) {
      unsigned short lo = f2bf(t[n][co + 2 * j]);
      unsigned short hi = f2bf(t[n][co + 2 * j + 1]);
      ow[j] = (unsigned int)lo | ((unsigned int)hi << 16);
    }
    uint4 o; o.x = ow[0]; o.y = ow[1]; o.z = ow[2]; o.w = ow[3];
    *(uint4*)&hT[bbh + (long)(n0 + n) * CDIM + c0 + co] = o;
  }
}

// ---------------- merged prep: wq/wk/wv fp32->bf16 + bias concat ----------------
__global__ __launch_bounds__(256) void prep_kernel(
    const float* __restrict__ wq, const float* __restrict__ wk,
    const float* __restrict__ wv, const float* __restrict__ bq,
    const float* __restrict__ bk, unsigned short* __restrict__ wqkb,
    unsigned short* __restrict__ wvb, float* __restrict__ bqk) {
  int blk = blockIdx.x;
  if (blk < 768) {
    int i = blk * 256 + threadIdx.x;
    const float* src = (blk < 256) ? wq : (blk < 512) ? wk : wv;
    unsigned short* dst = (blk < 256) ? wqkb : (blk < 512) ? (wqkb + 262144) : wvb;
    int j = i - ((blk < 256) ? 0 : (blk < 512) ? 65536 : 131072);
    float4 d = ((const float4*)src)[j];
    ushort4 o;
    o.x = f2bf(d.x); o.y = f2bf(d.y); o.z = f2bf(d.z); o.w = f2bf(d.w);
    ((ushort4*)dst)[j] = o;
  } else {
#pragma unroll
    for (int k = 0; k < 4; ++k) {
      int i = threadIdx.x + k * 256;
      bqk[i] = (i < 512) ? bq[i] : bk[i - 512];
    }
  }
}

// ---------------- fp32 -> bf16 convert (wp, launched late) ----------------
__global__ __launch_bounds__(256) void cvt_kernel(
    const float* __restrict__ src, unsigned short* __restrict__ dst, int n4) {
  int i = blockIdx.x * 256 + threadIdx.x;
  if (i >= n4) return;
  float4 d = ((const float4*)src)[i];
  ushort4 o;
  o.x = f2bf(d.x); o.y = f2bf(d.y); o.z = f2bf(d.z); o.w = f2bf(d.w);
  ((ushort4*)dst)[i] = o;
}

// ---------------- pipelined NT GEMM, 8 waves, 4-slot LDS ring ----------------
// C[M,Nn] = A[M,K] * B[Nn,K]^T, bf16 operands, row strides lA/lB.
// K in 32-wide chunks; chunk c in ring slot c&3, staged 3 ahead.  Fragment
// registers are DOUBLE-BUFFERED: segment d computes chunk d from regCur while
// issuing the ds_reads of chunk d+1 into regNext, so LDS-read latency hides
// under the ~1240-cyc MFMA cluster (round 3: serial reads->wait->MFMA left
// MfmaUtil at 30%).  Per segment:
//   vmcnt(L)   -- own chunk-(d+1) stages complete (L = loads/chunk/thread)
//   s_barrier  -- all waves: chunk d+1 staged; all waves done reading slot
//                 (d-1)&3 (their reads(d-1) were lgkm-confirmed in their
//                 segment d-1) -> stage(d+3) overwrite of slot (d-1)&3 safe
//   stage(d+3)
//   lgkmcnt(0) -- reads(d) (issued one segment ago) complete: ~free
//   sched_barrier; issue reads(d+1)->regNext; sched_barrier
//   setprio(1) MFMA(d) from regCur setprio(0)
// No "memory" clobbers in the loop (SIInsertWaitcnts would insert vmcnt(0)).
// LDS swizzle: rows are 64 B; 4-bank-group index = 16*(row&1) + 4*granule,
// so XOR key = (row>>1)&3 on both staging source and read (0 conflicts).
// EPI: 0 bf16 + bias[col]; 1 bf16 + bias[row]; 2 bf16 exp(val*scale);
//      3 bf16 val/rowsum (ones-MFMA); 4 fp32 + bias[row] + residual X.
// ORD: 0 = bx fastest in g, 1 = by fastest (L2 panel-reuse choice).
template <int BM, int BN, int EPI, int ORD>
__global__ __launch_bounds__(512, 2) void gemm8(
    const unsigned short* __restrict__ A, long sA, int lA,
    const unsigned short* __restrict__ B, long sB, int lB,
    void* __restrict__ Cp, long sC,
    const float* __restrict__ bias,
    const float* __restrict__ X, long sX,
    int GX, int GY, int Nn, int K) {
  constexpr int TM = BM / 32;          // frag rows per wave (8 or 4)
  constexpr int TN = BN / 64;          // frag cols per wave (4)
  constexpr int LA = BM / 128;         // global_load_lds per thread per A-chunk
  constexpr int LB = BN / 128;
  constexpr int L  = LA + LB;          // loads per chunk per thread (4 or 3)

  __shared__ __align__(16) unsigned short As[4 * BM * 32];
  __shared__ __align__(16) unsigned short Bs[4 * BN * 32];

  const int tid = threadIdx.x;
  const int nwg = gridDim.x;
  // bijective XCD-chunk mapping (nwg % 8 == 0 for all launches)
  const int g = (blockIdx.x & 7) * (nwg >> 3) + (blockIdx.x >> 3);
  int bx, by, bz;
  if (ORD == 0) { bx = g % GX; int t = g / GX; by = t % GY; bz = t / GY; }
  else          { by = g % GY; int t = g / GY; bx = t % GX; bz = t / GX; }

  A += (long)bz * sA;
  B += (long)bz * sB;
  const int m0 = by * BM;
  const int n0 = bx * BN;
  const int lane = tid & 63;
  const int wv = tid >> 6;
  const int wm = (wv >> 2) * (BM / 2);
  const int wn = (wv & 3) * (BN / 4);
  const int l16 = lane & 15;
  const int quad = lane >> 4;
  const int rdo = ((quad ^ ((l16 >> 1) & 3)) << 3);  // swizzled read granule

  // staging: per load, 512 threads cover 128 rows x 4 granules (16B each)
  const int rl = tid >> 2;             // row within 128-row group
  const int gl = tid & 3;              // physical granule slot
  const int swl = ((gl ^ ((rl >> 1) & 3)) << 3);     // inverse-swizzled source
  const unsigned short* Ag = A + (long)(m0 + rl) * lA + swl;
  const unsigned short* Bg = B + (long)(n0 + rl) * lB + swl;
  unsigned short* Asl = As + wv * 512;         // wave-uniform LDS dest base
  unsigned short* Bsl = Bs + wv * 512;

  const int nchunk = K >> 5;

  auto stage = [&](int c) {
    if (c < nchunk) {
#pragma unroll
      for (int i = 0; i < LA; ++i)
        __builtin_amdgcn_global_load_lds(
            (const gu32*)(Ag + (long)i * 128 * lA + c * 32),
            (lu32*)(Asl + (c & 3) * (BM * 32) + i * 4096), 16, 0, 0);
#pragma unroll
      for (int i = 0; i < LB; ++i)
        __builtin_amdgcn_global_load_lds(
            (const gu32*)(Bg + (long)i * 128 * lB + c * 32),
            (lu32*)(Bsl + (c & 3) * (BN * 32) + i * 4096), 16, 0, 0);
    }
  };

  f4v acc[TM][TN] = {};
  f4v accr[TM] = {};                   // EPI==3 row-sums (DCE'd otherwise)
  bf8v ones;
#pragma unroll
  for (int i = 0; i < 8; ++i) ones[i] = (__bf16)1.0f;

  bf8v afA[TM], bfA[TN], afB[TM], bfB[TN];

  auto readfr = [&](int c, bf8v* af, bf8v* bf) {
    const unsigned short* Ab = As + (c & 3) * (BM * 32);
    const unsigned short* Bb = Bs + (c & 3) * (BN * 32);
#pragma unroll
    for (int t = 0; t < TM; ++t)
      af[t] = lds_read16(&Ab[(wm + t * 16 + l16) * 32 + rdo]);
#pragma unroll
    for (int t = 0; t < TN; ++t)
      bf[t] = lds_read16(&Bb[(wn + t * 16 + l16) * 32 + rdo]);
  };

  auto mfma = [&](const bf8v* af, const bf8v* bf) {
    __builtin_amdgcn_s_setprio(1);
#pragma unroll
    for (int tm = 0; tm < TM; ++tm) {
#pragma unroll
      for (int tn = 0; tn < TN; ++tn)
        acc[tm][tn] = __builtin_amdgcn_mfma_f32_16x16x32_bf16(
            af[tm], bf[tn], acc[tm][tn], 0, 0, 0);
      if (EPI == 3)
        accr[tm] = __builtin_amdgcn_mfma_f32_16x16x32_bf16(
            af[tm], ones, accr[tm], 0, 0, 0);
    }
    __builtin_amdgcn_s_setprio(0);
  };

  // one pipeline segment: compute chunk d (cur regs), read chunk d+1 (nxt)
  auto seg = [&](int d, const bf8v* afC, const bf8v* bfC,
                 bf8v* afN, bf8v* bfN) {
    __builtin_amdgcn_s_barrier();
    stage(d + 3);
    asm volatile("s_waitcnt lgkmcnt(0)");
    __builtin_amdgcn_sched_barrier(0);
    readfr(d + 1, afN, bfN);
    __builtin_amdgcn_sched_barrier(0);
    mfma(afC, bfC);
  };

  // prologue: stage chunks 0..2, wait chunk 0, read its fragments
  stage(0); stage(1); stage(2);
  if constexpr (L == 4) asm volatile("s_waitcnt vmcnt(8)");
  else                  asm volatile("s_waitcnt vmcnt(6)");
  __builtin_amdgcn_s_barrier();
  readfr(0, afA, bfA);

  int d = 0;
  for (; d < nchunk - 2; d += 2) {
    if constexpr (L == 4) asm volatile("s_waitcnt vmcnt(4)");
    else                  asm volatile("s_waitcnt vmcnt(3)");
    seg(d, afA, bfA, afB, bfB);
    if constexpr (L == 4) asm volatile("s_waitcnt vmcnt(4)");
    else                  asm volatile("s_waitcnt vmcnt(3)");
    seg(d + 1, afB, bfB, afA, bfA);
  }
  // tail segment nchunk-2: last staged chunk is nchunk-1
  asm volatile("s_waitcnt vmcnt(0)");
  seg(d, afA, bfA, afB, bfB);
  // tail segment nchunk-1: nothing to stage or read
  asm volatile("s_waitcnt lgkmcnt(0)");
  __builtin_amdgcn_sched_barrier(0);
  mfma(afB, bfB);

  // C/D layout (verified m89/m91): col = lane&15, row = quad*4 + reg
  if (EPI == 2) {
#pragma unroll
    for (int tm = 0; tm < TM; ++tm) {
#pragma unroll
      for (int r = 0; r < 4; ++r) {
        const int row = m0 + wm + tm * 16 + quad * 4 + r;
#pragma unroll
        for (int tn = 0; tn < TN; ++tn) {
          const int col = n0 + wn + tn * 16 + l16;
          float e = __expf(acc[tm][tn][r] * 0.044194173824159216f);
          ((unsigned short*)Cp)[(long)bz * sC + (long)row * Nn + col] = f2bf(e);
        }
      }
    }
  } else if (EPI == 3) {
#pragma unroll
    for (int tm = 0; tm < TM; ++tm) {
#pragma unroll
      for (int r = 0; r < 4; ++r) {
        const int row = m0 + wm + tm * 16 + quad * 4 + r;
        const float inv = 1.0f / accr[tm][r];
#pragma unroll
        for (int tn = 0; tn < TN; ++tn) {
          const int col = n0 + wn + tn * 16 + l16;
          ((unsigned short*)Cp)[(long)bz * sC + (long)row * Nn + col] =
              f2bf(acc[tm][tn][r] * inv);
        }
      }
    }
  } else {
#pragma unroll
    for (int tm = 0; tm < TM; ++tm) {
#pragma unroll
      for (int tn = 0; tn < TN; ++tn) {
        const int col = n0 + wn + tn * 16 + l16;
#pragma unroll
        for (int r = 0; r < 4; ++r) {
          const int row = m0 + wm + tm * 16 + quad * 4 + r;
          float val = acc[tm][tn][r];
          if (EPI == 0) {
            val += bias[col];
            ((unsigned short*)Cp)[(long)bz * sC + (long)row * Nn + col] = f2bf(val);
          } else if (EPI == 1) {
            val += bias[row];
            ((unsigned short*)Cp)[(long)bz * sC + (long)row * Nn + col] = f2bf(val);
          } else {
            ((float*)Cp)[(long)bz * sC + (long)row * Nn + col] =
                val + bias[row] + X[(long)bz * sX + (long)row * Nn + col];
          }
        }
      }
    }
  }
}

extern "C" void kernel_launch(void* const* d_in, const int* in_sizes, int n_in,
                              void* d_out, int out_size, void* d_ws, size_t ws_size,
                              hipStream_t stream) {
  (void)in_sizes; (void)n_in; (void)out_size;
  const float* x  = (const float*)d_in[0];
  const float* gs = (const float*)d_in[1];
  const float* gb = (const float*)d_in[2];
  const float* wq = (const float*)d_in[3];
  const float* bq = (const float*)d_in[4];
  const float* wk = (const float*)d_in[5];
  const float* bk = (const float*)d_in[6];
  const float* wv = (const float*)d_in[7];
  const float* bv = (const float*)d_in[8];
  const float* wp = (const float*)d_in[9];
  const float* bp = (const float*)d_in[10];
  float* out = (float*)d_out;

  char* ws = (char*)d_ws;
  const long NC  = (long)NDIM * CDIM;        // per-batch [N,C] elems
  const long NQK = (long)NDIM * 1024;        // per-batch [N,1024] elems
  const long BUF = NC * 2 * BATCH;           // [B,N,C] bf16 buffer = 16,777,216 B
  const long NN  = (long)NDIM * NDIM;

  // Layout (aliased):
  //   [0, BUF)        hT, later OT
  //   [BUF, 3BUF)     qkT [B,N,1024]; later wpb overlays its head
  //   [3BUF, 4BUF)    vB [B,C,N]
  //   [4BUF, ...)     sc: bf16 unnormalized exp-scores P'; head doubles as
  //                   wqkb/wvb/bqk/stats (all dead before scores GEMM writes)
  unsigned short* hT   = (unsigned short*)(ws);
  unsigned short* OT   = hT;
  unsigned short* qkT  = (unsigned short*)(ws + BUF);
  unsigned short* vB   = (unsigned short*)(ws + BUF * 3);
  unsigned short* sc   = (unsigned short*)(ws + BUF * 4);
  unsigned short* wqkb = sc;                                   // 1 MB
  unsigned short* wvb  = (unsigned short*)(ws + BUF * 4 + 1048576);
  float* bqk           = (float*)(ws + BUF * 4 + 1572864);
  float* stats         = (float*)(ws + BUF * 4 + 1581056);
  unsigned short* wpb  = qkT;  // overlays dead qkT for final proj

  gn_stats_kernel<<<BATCH * 32, 256, 0, stream>>>(x, stats);
  gn_transpose_kernel<<<dim3(NDIM / 64, CDIM / 64, BATCH), 256, 0, stream>>>(x, gs, gb, stats, hT);
  prep_kernel<<<769, 256, 0, stream>>>(wq, wk, wv, bq, bk, wqkb, wvb, bqk);

  // qkT = hT * [wq;wk]^T + bqk  ([N,1024]) : 4x16x4 tiles = 256 blocks
  gemm8<256, 256, 0, 0><<<256, 512, 0, stream>>>(
      hT, NC, CDIM, wqkb, 0, CDIM, qkT, NQK, bqk, nullptr, 0, 4, 16, 1024, CDIM);
  // v = wv * hT^T + bv  ([C,N]) : 16x4x4 = 256 blocks
  gemm8<128, 256, 1, 1><<<256, 512, 0, stream>>>(
      wvb, 0, CDIM, hT, NC, CDIM, vB, NC, bv, nullptr, 0, 16, 4, NDIM, CDIM);

  if (ws_size >= (size_t)(BUF * 4) + (size_t)(NN * 2) * BATCH) {
    // Primary (192 MiB): fully batched attention, softmax fused away.
    gemm8<256, 256, 2, 0><<<1024, 512, 0, stream>>>(
        qkT, NQK, 1024, qkT + 512, NQK, 1024, sc, NN, nullptr, nullptr, 0,
        16, 16, NDIM, CDIM);
    gemm8<128, 256, 3, 1><<<256, 512, 0, stream>>>(
        sc, NN, NDIM, vB, NC, NDIM, OT, NC, nullptr, nullptr, 0,
        2, 32, CDIM, NDIM);
  } else {
    // Fallback (~101 MB): per-batch rounds.
    for (int b = 0; b < BATCH; ++b) {
      gemm8<256, 256, 2, 0><<<256, 512, 0, stream>>>(
          qkT + b * NQK, 0, 1024, qkT + b * NQK + 512, 0, 1024, sc, 0,
          nullptr, nullptr, 0, 16, 16, NDIM, CDIM);
      gemm8<128, 256, 3, 1><<<64, 512, 0, stream>>>(
          sc, 0, NDIM, vB + b * NC, 0, NDIM, OT + b * NC, 0,
          nullptr, nullptr, 0, 2, 32, CDIM, NDIM);
    }
  }

  // out = wp * OT^T + bp + x  (fp32 out, fused residual); wpb overlays dead qkT
  cvt_kernel<<<256, 256, 0, stream>>>(wp, wpb, 65536);
  gemm8<128, 256, 4, 1><<<256, 512, 0, stream>>>(
      wpb, 0, CDIM, OT, NC, CDIM, out, NC, bp, x, NC, 16, 4, NDIM, CDIM);
}

// Round 5
// 354.135 us; speedup vs baseline: 1.0251x; 1.0251x over previous
//
#include <hip/hip_runtime.h>

#define CDIM 512
#define NDIM 4096
#define BATCH 4

using bf8v = __attribute__((ext_vector_type(8))) __bf16;
using f4v  = __attribute__((ext_vector_type(4))) float;

typedef __attribute__((address_space(1))) unsigned int gu32;
typedef __attribute__((address_space(3))) unsigned int lu32;

static __device__ __forceinline__ unsigned short f2bf(float f) {
  unsigned int u = __float_as_uint(f);
  u += 0x7fffu + ((u >> 16) & 1u);   // round-to-nearest-even
  return (unsigned short)(u >> 16);
}

// inline-asm LDS read: invisible to SIInsertWaitcnts' LDS-DMA tracking, so no
// conservative vmcnt(0) is inserted while global_load_lds prefetches are in
// flight.  Data validity is guaranteed by the explicit vmcnt/barrier/lgkmcnt
// protocol in the K-loop.
static __device__ __forceinline__ bf8v lds_read16(const unsigned short* p) {
  bf8v r;
  unsigned off = (unsigned)(unsigned long long)p;
  asm volatile("ds_read_b128 %0, %1" : "=v"(r) : "v"(off));
  return r;
}

// ---------------- GN pass 1: per-(b,g) mean/rstd ----------------
__global__ __launch_bounds__(256) void gn_stats_kernel(
    const float* __restrict__ x, float* __restrict__ stats) {
  const int tid = threadIdx.x;
  const float4* xv = (const float4*)(x + (long)blockIdx.x * 65536);
  float s = 0.f, ss = 0.f;
  for (int i = tid; i < 16384; i += 256) {
    float4 d = xv[i];
    s  += d.x + d.y + d.z + d.w;
    ss += d.x * d.x + d.y * d.y + d.z * d.z + d.w * d.w;
  }
#pragma unroll
  for (int off = 32; off; off >>= 1) {
    s  += __shfl_down(s, off);
    ss += __shfl_down(ss, off);
  }
  __shared__ float red[8];
  if ((tid & 63) == 0) { red[tid >> 6] = s; red[4 + (tid >> 6)] = ss; }
  __syncthreads();
  if (tid == 0) {
    float S  = red[0] + red[1] + red[2] + red[3];
    float SS = red[4] + red[5] + red[6] + red[7];
    float mean = S * (1.f / 65536.f);
    float var  = SS * (1.f / 65536.f) - mean * mean;
    stats[blockIdx.x * 2]     = mean;
    stats[blockIdx.x * 2 + 1] = rsqrtf(var + 1e-6f);
  }
}

// ---------------- GN pass 2: normalize + transpose, fp32 [C,N] -> bf16 [N,C] ----------------
__global__ __launch_bounds__(256) void gn_transpose_kernel(
    const float* __restrict__ x, const float* __restrict__ gs,
    const float* __restrict__ gb, const float* __restrict__ stats,
    unsigned short* __restrict__ hT) {
  __shared__ float t[64][65];
  const int tid = threadIdx.x;
  const int b = blockIdx.z;
  const long bbx = (long)b * ((long)CDIM * NDIM);
  const int n0 = blockIdx.x * 64, c0 = blockIdx.y * 64;
  for (int k = 0; k < 4; ++k) {
    int it = tid + k * 256;
    int c = it >> 4, no = (it & 15) << 2;
    int ch = c0 + c;
    int g = ch >> 4;
    float mean = stats[(b * 32 + g) * 2];
    float rstd = stats[(b * 32 + g) * 2 + 1];
    float a  = rstd * gs[ch];
    float bb = gb[ch] - mean * a;
    float4 d = *(const float4*)&x[bbx + (long)ch * NDIM + n0 + no];
    t[no + 0][c] = d.x * a + bb;
    t[no + 1][c] = d.y * a + bb;
    t[no + 2][c] = d.z * a + bb;
    t[no + 3][c] = d.w * a + bb;
  }
  __syncthreads();
  const long bbh = (long)b * ((long)NDIM * CDIM);
  for (int k = 0; k < 2; ++k) {
    int it = tid + k * 256;
    int n = it >> 3, co = (it & 7) << 3;
    unsigned int ow[4];
#pragma unroll
    for (int j = 0; j < 4; ++j) {
      unsigned short lo = f2bf(t[n][co + 2 * j]);
      unsigned short hi = f2bf(t[n][co + 2 * j + 1]);
      ow[j] = (unsigned int)lo | ((unsigned int)hi << 16);
    }
    uint4 o; o.x = ow[0]; o.y = ow[1]; o.z = ow[2]; o.w = ow[3];
    *(uint4*)&hT[bbh + (long)(n0 + n) * CDIM + c0 + co] = o;
  }
}

// ---------------- merged prep: wq/wk/wv fp32->bf16 + bias concat ----------------
__global__ __launch_bounds__(256) void prep_kernel(
    const float* __restrict__ wq, const float* __restrict__ wk,
    const float* __restrict__ wv, const float* __restrict__ bq,
    const float* __restrict__ bk, unsigned short* __restrict__ wqkb,
    unsigned short* __restrict__ wvb, float* __restrict__ bqk) {
  int blk = blockIdx.x;
  if (blk < 768) {
    int i = blk * 256 + threadIdx.x;
    const float* src = (blk < 256) ? wq : (blk < 512) ? wk : wv;
    unsigned short* dst = (blk < 256) ? wqkb : (blk < 512) ? (wqkb + 262144) : wvb;
    int j = i - ((blk < 256) ? 0 : (blk < 512) ? 65536 : 131072);
    float4 d = ((const float4*)src)[j];
    ushort4 o;
    o.x = f2bf(d.x); o.y = f2bf(d.y); o.z = f2bf(d.z); o.w = f2bf(d.w);
    ((ushort4*)dst)[j] = o;
  } else {
#pragma unroll
    for (int k = 0; k < 4; ++k) {
      int i = threadIdx.x + k * 256;
      bqk[i] = (i < 512) ? bq[i] : bk[i - 512];
    }
  }
}

// ---------------- fp32 -> bf16 convert (wp, launched late) ----------------
__global__ __launch_bounds__(256) void cvt_kernel(
    const float* __restrict__ src, unsigned short* __restrict__ dst, int n4) {
  int i = blockIdx.x * 256 + threadIdx.x;
  if (i >= n4) return;
  float4 d = ((const float4*)src)[i];
  ushort4 o;
  o.x = f2bf(d.x); o.y = f2bf(d.y); o.z = f2bf(d.z); o.w = f2bf(d.w);
  ((ushort4*)dst)[i] = o;
}

// ---------------- NT GEMM: BK=64 tiles, 2-slot dbuf, quadrant-phase K-loop ----------------
// C[M,Nn] = A[M,K] * B[Nn,K]^T, bf16, row strides lA/lB.
// K in 64-wide tiles; tile t in LDS slot t&1, staged one tile ahead.  Per tile
// ONE boundary {vmcnt(0) [stale: stage(t) issued a full tile ago -> ~free] ->
// s_barrier -> stage(t+1)} then TM/2 quadrant-phases with NO barriers: frag
// reads always issued one 16-MFMA cluster ahead, gated by counted lgkmcnt(4)
// + sched_barrier(0) (rule #18), setprio(1) around each cluster.  Rounds 2-4
// showed per-32-chunk barriers+waits cost ~1.9k cyc/chunk with 2 waves/SIMD
// in lockstep (MfmaUtil pinned at 28-31% across 3 schedule variants); this
// halves boundary count and lets waves drift within the tile.
// Slot safety: stage(t+1) (slot s^1) issues only after the boundary barrier;
// every wave's reads of slot s^1 (tile t-1) were lgkm-confirmed before its
// last MFMA of t-1, which precedes its barrier arrival.
// LDS swizzle: rows are 128 B (8 x 16B granules); read granule G at row R is
// stored at G^(R&7) (stage source pre-swizzled with the same involution) ->
// 16-lane groups spread over all 8 granule positions, 2 lanes each (free).
// EPI: 0 bf16 + bias[col]; 1 bf16 + bias[row]; 2 bf16 exp(val*scale);
//      3 bf16 val/rowsum (ones-MFMA); 4 fp32 + bias[row] + residual X.
// ORD: 0 = bx fastest in g, 1 = by fastest (L2 panel-reuse choice).
template <int BM, int BN, int EPI, int ORD>
__global__ __launch_bounds__(512, 2) void gemm8(
    const unsigned short* __restrict__ A, long sA, int lA,
    const unsigned short* __restrict__ B, long sB, int lB,
    void* __restrict__ Cp, long sC,
    const float* __restrict__ bias,
    const float* __restrict__ X, long sX,
    int GX, int GY, int Nn, int K) {
  constexpr int TM = BM / 32;          // frag rows per wave (8 or 4)
  constexpr int TN = BN / 64;          // frag cols per wave (4)
  constexpr int LA = BM / 64;          // A gloads per thread per K-tile (4 or 2)
  constexpr int LB = BN / 64;          // B gloads per thread per K-tile (4)

  __shared__ __align__(16) unsigned short As[2 * BM * 64];
  __shared__ __align__(16) unsigned short Bs[2 * BN * 64];

  const int tid = threadIdx.x;
  const int nwg = gridDim.x;
  // bijective XCD-chunk mapping (nwg % 8 == 0 for all launches)
  const int g = (blockIdx.x & 7) * (nwg >> 3) + (blockIdx.x >> 3);
  int bx, by, bz;
  if (ORD == 0) { bx = g % GX; int t = g / GX; by = t % GY; bz = t / GY; }
  else          { by = g % GY; int t = g / GY; bx = t % GX; bz = t / GX; }

  A += (long)bz * sA;
  B += (long)bz * sB;
  const int m0 = by * BM;
  const int n0 = bx * BN;
  const int lane = tid & 63;
  const int wv = tid >> 6;
  const int wm = (wv >> 2) * (BM / 2);
  const int wn = (wv & 3) * (BN / 4);
  const int l16 = lane & 15;
  const int quad = lane >> 4;
  const int sw7 = l16 & 7;
  const int rg0 = ((0 + quad) ^ sw7) << 3;   // kk=0 swizzled granule, elems
  const int rg1 = ((4 + quad) ^ sw7) << 3;   // kk=1

  // staging: load i covers granule-slots i*512+tid of a [rows][8] granule grid
  const int r0s  = wv * 8 + (lane >> 3);              // base row for this lane
  const int gsrc = ((lane & 7) ^ (lane >> 3)) << 3;   // pre-swizzled source, elems
  const unsigned short* Ag = A + (long)(m0 + r0s) * lA + gsrc;
  const unsigned short* Bg = B + (long)(n0 + r0s) * lB + gsrc;

  const int nt = K >> 6;

  auto stage = [&](int t) {
    if (t < nt) {
      const int k0 = t << 6;
      unsigned short* Ad = As + (t & 1) * (BM * 64) + wv * 512;
      unsigned short* Bd = Bs + (t & 1) * (BN * 64) + wv * 512;
#pragma unroll
      for (int i = 0; i < LA; ++i)
        __builtin_amdgcn_global_load_lds(
            (const gu32*)(Ag + (long)i * 64 * lA + k0),
            (lu32*)(Ad + i * 4096), 16, 0, 0);
#pragma unroll
      for (int i = 0; i < LB; ++i)
        __builtin_amdgcn_global_load_lds(
            (const gu32*)(Bg + (long)i * 64 * lB + k0),
            (lu32*)(Bd + i * 4096), 16, 0, 0);
    }
  };

  f4v acc[TM][TN] = {};
  f4v accr[TM] = {};                   // EPI==3 row-sums (DCE'd otherwise)
  bf8v ones;
#pragma unroll
  for (int i = 0; i < 8; ++i) ones[i] = (__bf16)1.0f;

  bf8v bfr[TN][2];
  bf8v afA[2][2], afB[2][2];           // quadrant ping-pong: [row-in-pair][kk]

  const unsigned short* Ab;
  const unsigned short* Bb;

  auto rdB = [&]() {
#pragma unroll
    for (int tn = 0; tn < TN; ++tn) {
      bfr[tn][0] = lds_read16(&Bb[(wn + tn * 16 + l16) * 64 + rg0]);
      bfr[tn][1] = lds_read16(&Bb[(wn + tn * 16 + l16) * 64 + rg1]);
    }
  };
  auto rdA = [&](int q, bf8v (&fr)[2][2]) {
#pragma unroll
    for (int dr = 0; dr < 2; ++dr) {
      fr[dr][0] = lds_read16(&Ab[(wm + (q * 2 + dr) * 16 + l16) * 64 + rg0]);
      fr[dr][1] = lds_read16(&Ab[(wm + (q * 2 + dr) * 16 + l16) * 64 + rg1]);
    }
  };
  auto clus = [&](int q, bf8v (&fr)[2][2]) {
    __builtin_amdgcn_s_setprio(1);
#pragma unroll
    for (int kk = 0; kk < 2; ++kk)
#pragma unroll
      for (int dr = 0; dr < 2; ++dr) {
        const int tm = q * 2 + dr;
#pragma unroll
        for (int tn = 0; tn < TN; ++tn)
          acc[tm][tn] = __builtin_amdgcn_mfma_f32_16x16x32_bf16(
              fr[dr][kk], bfr[tn][kk], acc[tm][tn], 0, 0, 0);
        if (EPI == 3)
          accr[tm] = __builtin_amdgcn_mfma_f32_16x16x32_bf16(
              fr[dr][kk], ones, accr[tm], 0, 0, 0);
      }
    __builtin_amdgcn_s_setprio(0);
  };

  stage(0);
  for (int t = 0; t < nt; ++t) {
    asm volatile("s_waitcnt vmcnt(0)");          // stage(t): issued 1 tile ago
    __builtin_amdgcn_s_barrier();
    stage(t + 1);
    Ab = As + (t & 1) * (BM * 64);
    Bb = Bs + (t & 1) * (BN * 64);
    rdB();                                       // 8 reads
    rdA(0, afA);                                 // 4 reads
    if constexpr (TM == 8) {
      rdA(1, afB);
      asm volatile("s_waitcnt lgkmcnt(4)");      // B + q0 done (q1 in flight)
      __builtin_amdgcn_sched_barrier(0);
      clus(0, afA);
      rdA(2, afA);
      asm volatile("s_waitcnt lgkmcnt(4)");      // q1 done (q2 in flight)
      __builtin_amdgcn_sched_barrier(0);
      clus(1, afB);
      rdA(3, afB);
      asm volatile("s_waitcnt lgkmcnt(4)");      // q2 done (q3 in flight)
      __builtin_amdgcn_sched_barrier(0);
      clus(2, afA);
      asm volatile("s_waitcnt lgkmcnt(0)");      // q3 done
      __builtin_amdgcn_sched_barrier(0);
      clus(3, afB);
    } else {
      rdA(1, afB);
      asm volatile("s_waitcnt lgkmcnt(4)");      // B + p0 done (p1 in flight)
      __builtin_amdgcn_sched_barrier(0);
      clus(0, afA);
      asm volatile("s_waitcnt lgkmcnt(0)");      // p1 done
      __builtin_amdgcn_sched_barrier(0);
      clus(1, afB);
    }
  }

  // C/D layout (verified m89/m91): col = lane&15, row = quad*4 + reg
  if (EPI == 2) {
#pragma unroll
    for (int tm = 0; tm < TM; ++tm) {
#pragma unroll
      for (int r = 0; r < 4; ++r) {
        const int row = m0 + wm + tm * 16 + quad * 4 + r;
#pragma unroll
        for (int tn = 0; tn < TN; ++tn) {
          const int col = n0 + wn + tn * 16 + l16;
          float e = __expf(acc[tm][tn][r] * 0.044194173824159216f);
          ((unsigned short*)Cp)[(long)bz * sC + (long)row * Nn + col] = f2bf(e);
        }
      }
    }
  } else if (EPI == 3) {
#pragma unroll
    for (int tm = 0; tm < TM; ++tm) {
#pragma unroll
      for (int r = 0; r < 4; ++r) {
        const int row = m0 + wm + tm * 16 + quad * 4 + r;
        const float inv = 1.0f / accr[tm][r];
#pragma unroll
        for (int tn = 0; tn < TN; ++tn) {
          const int col = n0 + wn + tn * 16 + l16;
          ((unsigned short*)Cp)[(long)bz * sC + (long)row * Nn + col] =
              f2bf(acc[tm][tn][r] * inv);
        }
      }
    }
  } else {
#pragma unroll
    for (int tm = 0; tm < TM; ++tm) {
#pragma unroll
      for (int tn = 0; tn < TN; ++tn) {
        const int col = n0 + wn + tn * 16 + l16;
#pragma unroll
        for (int r = 0; r < 4; ++r) {
          const int row = m0 + wm + tm * 16 + quad * 4 + r;
          float val = acc[tm][tn][r];
          if (EPI == 0) {
            val += bias[col];
            ((unsigned short*)Cp)[(long)bz * sC + (long)row * Nn + col] = f2bf(val);
          } else if (EPI == 1) {
            val += bias[row];
            ((unsigned short*)Cp)[(long)bz * sC + (long)row * Nn + col] = f2bf(val);
          } else {
            ((float*)Cp)[(long)bz * sC + (long)row * Nn + col] =
                val + bias[row] + X[(long)bz * sX + (long)row * Nn + col];
          }
        }
      }
    }
  }
}

extern "C" void kernel_launch(void* const* d_in, const int* in_sizes, int n_in,
                              void* d_out, int out_size, void* d_ws, size_t ws_size,
                              hipStream_t stream) {
  (void)in_sizes; (void)n_in; (void)out_size;
  const float* x  = (const float*)d_in[0];
  const float* gs = (const float*)d_in[1];
  const float* gb = (const float*)d_in[2];
  const float* wq = (const float*)d_in[3];
  const float* bq = (const float*)d_in[4];
  const float* wk = (const float*)d_in[5];
  const float* bk = (const float*)d_in[6];
  const float* wv = (const float*)d_in[7];
  const float* bv = (const float*)d_in[8];
  const float* wp = (const float*)d_in[9];
  const float* bp = (const float*)d_in[10];
  float* out = (float*)d_out;

  char* ws = (char*)d_ws;
  const long NC  = (long)NDIM * CDIM;        // per-batch [N,C] elems
  const long NQK = (long)NDIM * 1024;        // per-batch [N,1024] elems
  const long BUF = NC * 2 * BATCH;           // [B,N,C] bf16 buffer = 16,777,216 B
  const long NN  = (long)NDIM * NDIM;

  // Layout (aliased):
  //   [0, BUF)        hT, later OT
  //   [BUF, 3BUF)     qkT [B,N,1024]; later wpb overlays its head
  //   [3BUF, 4BUF)    vB [B,C,N]
  //   [4BUF, ...)     sc: bf16 unnormalized exp-scores P'; head doubles as
  //                   wqkb/wvb/bqk/stats (all dead before scores GEMM writes)
  unsigned short* hT   = (unsigned short*)(ws);
  unsigned short* OT   = hT;
  unsigned short* qkT  = (unsigned short*)(ws + BUF);
  unsigned short* vB   = (unsigned short*)(ws + BUF * 3);
  unsigned short* sc   = (unsigned short*)(ws + BUF * 4);
  unsigned short* wqkb = sc;                                   // 1 MB
  unsigned short* wvb  = (unsigned short*)(ws + BUF * 4 + 1048576);
  float* bqk           = (float*)(ws + BUF * 4 + 1572864);
  float* stats         = (float*)(ws + BUF * 4 + 1581056);
  unsigned short* wpb  = qkT;  // overlays dead qkT for final proj

  gn_stats_kernel<<<BATCH * 32, 256, 0, stream>>>(x, stats);
  gn_transpose_kernel<<<dim3(NDIM / 64, CDIM / 64, BATCH), 256, 0, stream>>>(x, gs, gb, stats, hT);
  prep_kernel<<<769, 256, 0, stream>>>(wq, wk, wv, bq, bk, wqkb, wvb, bqk);

  // qkT = hT * [wq;wk]^T + bqk  ([N,1024]) : 4x16x4 tiles = 256 blocks
  gemm8<256, 256, 0, 0><<<256, 512, 0, stream>>>(
      hT, NC, CDIM, wqkb, 0, CDIM, qkT, NQK, bqk, nullptr, 0, 4, 16, 1024, CDIM);
  // v = wv * hT^T + bv  ([C,N]) : 16x4x4 = 256 blocks
  gemm8<128, 256, 1, 1><<<256, 512, 0, stream>>>(
      wvb, 0, CDIM, hT, NC, CDIM, vB, NC, bv, nullptr, 0, 16, 4, NDIM, CDIM);

  if (ws_size >= (size_t)(BUF * 4) + (size_t)(NN * 2) * BATCH) {
    // Primary (192 MiB): fully batched attention, softmax fused away.
    gemm8<256, 256, 2, 0><<<1024, 512, 0, stream>>>(
        qkT, NQK, 1024, qkT + 512, NQK, 1024, sc, NN, nullptr, nullptr, 0,
        16, 16, NDIM, CDIM);
    gemm8<128, 256, 3, 1><<<256, 512, 0, stream>>>(
        sc, NN, NDIM, vB, NC, NDIM, OT, NC, nullptr, nullptr, 0,
        2, 32, CDIM, NDIM);
  } else {
    // Fallback (~101 MB): per-batch rounds.
    for (int b = 0; b < BATCH; ++b) {
      gemm8<256, 256, 2, 0><<<256, 512, 0, stream>>>(
          qkT + b * NQK, 0, 1024, qkT + b * NQK + 512, 0, 1024, sc, 0,
          nullptr, nullptr, 0, 16, 16, NDIM, CDIM);
      gemm8<128, 256, 3, 1><<<64, 512, 0, stream>>>(
          sc, 0, NDIM, vB + b * NC, 0, NDIM, OT + b * NC, 0,
          nullptr, nullptr, 0, 2, 32, CDIM, NDIM);
    }
  }

  // out = wp * OT^T + bp + x  (fp32 out, fused residual); wpb overlays dead qkT
  cvt_kernel<<<256, 256, 0, stream>>>(wp, wpb, 65536);
  gemm8<128, 256, 4, 1><<<256, 512, 0, stream>>>(
      wpb, 0, CDIM, OT, NC, CDIM, out, NC, bp, x, NC, 16, 4, NDIM, CDIM);
}